// Round 12
// baseline (6051.283 us; speedup 1.0000x reference)
//
#include <hip/hip_runtime.h>
#include <math.h>

// ---------------- problem constants ----------------
#define HC 96
#define WC 96
#define CCH 64
#define BB 8
#define NL 8
#define IMG (HC*WC)                 // 9216
#define LSTRIDE (BB*CCH*IMG)        // 4,718,592
#define EPS 1e-5f

// padded-chunked NHWC bf16 layout: [b][ch2][y:98][x:98][ic:32]
#define PY 98
#define PX 98
#define ICH 32
#define PLANE (PY*PX*ICH)           // 307,328
#define PL (BB*2*PLANE)             // 4,917,248 els per layer tensor
#define APK_L (2*9*2*64*32)         // 73,728 els per layer per direction

// padded stats layout: per (b,oc) a 128B slot; s at +0, s2 at +16 floats.
#define STAT_STRIDE 32              // floats per (b,oc) slot
#define STAT_SLOT (512*STAT_STRIDE) // floats per layer-step slot (64 KB)

#define NBLK 768                    // 3 blocks/CU x 256 CUs, exact residency

typedef __bf16 bf16;
typedef bf16 bf16x8 __attribute__((ext_vector_type(8)));
typedef float f32x4 __attribute__((ext_vector_type(4)));

__device__ __forceinline__ float a_of(int i){ return sqrtf((i+1.f)/(i+2.f)); }
__device__ __forceinline__ float b_of(int i){ return sqrtf((float)i/(float)(i+1)); }

// ---------------------------------------------------------------------------
// Grid-wide barrier (all NBLK blocks co-resident by construction:
// grid=768, __launch_bounds__(256,3), 38.9KB LDS -> 3 blocks/CU guaranteed).
// Generation-counter arrive/spin; AGENT-scope atomics + __threadfence give
// the cross-XCD L2 writeback/invalidate (gfx950 per-XCD L2 non-coherent).
__device__ __forceinline__ void gsync(unsigned* bar, unsigned* gen){
  __syncthreads();
  if (threadIdx.x == 0){
    __threadfence();
    unsigned g = __hip_atomic_load(gen, __ATOMIC_RELAXED, __HIP_MEMORY_SCOPE_AGENT);
    unsigned a = __hip_atomic_fetch_add(bar, 1u, __ATOMIC_ACQ_REL, __HIP_MEMORY_SCOPE_AGENT);
    if (a == NBLK - 1u){
      __hip_atomic_store(bar, 0u, __ATOMIC_RELAXED, __HIP_MEMORY_SCOPE_AGENT);
      __hip_atomic_fetch_add(gen, 1u, __ATOMIC_ACQ_REL, __HIP_MEMORY_SCOPE_AGENT);
    } else {
      while (__hip_atomic_load(gen, __ATOMIC_ACQUIRE, __HIP_MEMORY_SCOPE_AGENT) == g){
        __builtin_amdgcn_s_sleep(2);
      }
    }
    __threadfence();
  }
  __syncthreads();
}

// ---------------------------------------------------------------------------
// Split weights into hi/lo bf16 planes, frag-friendly layout:
// apX[l][ch][tap][rep][oc64][ic32]. fwd: K[l][oc][ic][tap]; bwd: K[l][ic][oc][8-tap].
__global__ void pack_weights(const float* __restrict__ K,
                             bf16* __restrict__ apf, bf16* __restrict__ apb){
  int idx = blockIdx.x*256 + threadIdx.x;          // NL*9*64*64
  if (idx >= NL*9*64*64) return;
  int ic = idx & 63, oc = (idx>>6) & 63;
  int tap = (idx>>12) % 9, l = idx/(4096*9);
  float wf = K[(((size_t)l*64 + oc)*64 + ic)*9 + tap];
  float wb = K[(((size_t)l*64 + ic)*64 + oc)*9 + (8-tap)];
  int ch = ic>>5, ic5 = ic&31;
  size_t base = (size_t)l*APK_L + ((size_t)((ch*9 + tap)*2)*64 + oc)*32 + ic5;
  bf16 fh = (bf16)wf;
  apf[base] = fh; apf[base + 64*32] = (bf16)(wf - (float)fh);
  bf16 bh = (bf16)wb;
  apb[base] = bh; apb[base + 64*32] = (bf16)(wb - (float)bh);
}

// ---------------------------------------------------------------------------
// Fix-iter 0 constant-folded: Yf closed form from X, X0; writes padded NHWC bf16.
__global__ __launch_bounds__(256) void init_yf_t(const float* __restrict__ X,
                                                 const float* __restrict__ X0,
                                                 bf16* __restrict__ yfq){
  __shared__ float LX[64][97];
  __shared__ float L0[64][97];
  int b = blockIdx.y, y = blockIdx.x;
  for (int i = threadIdx.x; i < 64*96; i += 256){
    int c = i/96, x = i%96;
    LX[c][x] = X[(((size_t)b*64 + c)*96 + y)*96 + x];
    L0[c][x] = X0[((size_t)c*96 + y)*96 + x];
  }
  __syncthreads();
  for (int j = threadIdx.x; j < 96*64; j += 256){
    int x = j>>6, c = j&63;
    float xv = LX[c][x], x0v = L0[c][x];
    size_t eoff = ((size_t)(b*2 + (c>>5))*PY + (y+1))*(size_t)PX*ICH
                + (size_t)(x+1)*ICH + (c&31);
    float yf = 0.f;
#pragma unroll
    for (int i = 0; i < NL; i++){
      float yv = (i==0 ? x0v : 0.f) + (i==NL-1 ? xv : 0.f);
      yf = a_of(i)*(b_of(i)*yf + yv);
      yfq[(size_t)i*PL + eoff] = (bf16)yf;
    }
  }
}

// ---------------------------------------------------------------------------
// Backward scan over padded bf16 Yf->Z in place, grid-stride phase version.
__device__ void back_scan_phase(bf16* __restrict__ buf){
  for (size_t i8 = (size_t)blockIdx.x*256 + threadIdx.x; i8 < (size_t)PL/8;
       i8 += (size_t)NBLK*256){
    size_t base = i8*8;
    float c[8];
#pragma unroll
    for (int e=0;e<8;e++) c[e]=0.f;
#pragma unroll
    for (int l = NL-1; l >= 0; l--){
      float al = a_of(l);
      uint4 v = *(const uint4*)(buf + (size_t)l*PL + base);
      bf16* hp = (bf16*)&v;
      uint4 o; bf16* ho = (bf16*)&o;
#pragma unroll
      for (int e=0;e<8;e++){
        float z = al*(al*c[e] + (float)hp[e]);
        ho[e] = (bf16)z; c[e] = z;
      }
      *(uint4*)(buf + (size_t)l*PL + base) = o;
    }
  }
}

// Final backward scan: fp32 NCHW in zbase (d_out), emits out0 = Z[7].
__device__ void back_scan_final_phase(float* __restrict__ zbase,
                                      float* __restrict__ out0){
  for (size_t idx = (size_t)blockIdx.x*256 + threadIdx.x; idx < (size_t)LSTRIDE;
       idx += (size_t)NBLK*256){
    float c = 0.f;
#pragma unroll
    for (int i = NL-1; i >= 0; i--){
      float ai = a_of(i);
      float z = ai*(ai*c + zbase[(size_t)i*LSTRIDE + idx]);
      zbase[(size_t)i*LSTRIDE + idx] = z;
      if (i == NL-1) out0[idx] = z;
      c = z;
    }
  }
}

// ---------------------------------------------------------------------------
// R11's conv_mfma verbatim as a device function (1D block decode).
// MODE 0: in=Zq[l] -> dzq_out (padded bf16, LDS transpose) + fused stats
// MODE 1: in=dzq_in+stats; yv=-acc(+X/+X0); yf=a*(b*prev+yv) -> yfq_out
// MODE 2: same math fp32, direct NCHW stores to zb_out (final iteration)
template<int MODE>
__device__ void conv_body(char* smem, float (*sred)[32], float (*qred)[32],
    float2* stat_s,
    const bf16* __restrict__ inq, const bf16* __restrict__ dzq_in,
    const bf16* __restrict__ apk,
    bf16* __restrict__ dzq_out, float* __restrict__ accstat,
    bf16* __restrict__ yfq_out, const bf16* __restrict__ yfq_prev,
    float* __restrict__ zb_out, const float* __restrict__ zb_prev,
    const float* __restrict__ Xadd, const float* __restrict__ X0add,
    float a_i, float b_i)
{
  char* Bbc = smem;                        // [4 rows][98 px][32 ic] bf16, swizzled
  char* Abc = smem + 25088;                // [3 taps][2 rep][32 oc][32 ic] bf16, swz

  const int bx = blockIdx.x;
  const int rowg = bx % 48, b = (bx/48) & 7, h = bx/384;  // h = oc half
  const int y0 = rowg*2;
  const int tid = threadIdx.x;
  const int w = tid>>6, lane = tid&63;
  const int n16 = lane&15, q = lane>>4;
  const int wr = w>>1, wcol = (w&1)*48;
  const int yg = y0 + wr;

  if (MODE >= 1){   // finalize instance-norm stats for this b (padded slot)
    if (tid < 64){
      float s  = accstat[((size_t)b*64 + tid)*STAT_STRIDE];
      float s2 = accstat[((size_t)b*64 + tid)*STAT_STRIDE + 16];
      float m = s*(1.f/IMG);
      float vv = s2*(1.f/IMG) - m*m;
      if (vv < 0.f) vv = 0.f;
      stat_s[tid] = make_float2(m, rsqrtf(vv + EPS));
    }
    __syncthreads();
  }

  f32x4 acc[2][3];
#pragma unroll
  for (int a=0;a<2;a++)
#pragma unroll
    for (int c=0;c<3;c++){ f32x4 z = {0.f,0.f,0.f,0.f}; acc[a][c] = z; }

  for (int ch = 0; ch < 2; ch++){
    __syncthreads();
    if (MODE == 0){
      // stage 4 padded rows x 98 cols x 32 ic, swizzled 16B slots (raw bf16)
      const uint4* src = (const uint4*)(inq + (size_t)(b*2 + ch)*PLANE
                                            + (size_t)y0*PX*ICH);
      for (int i = tid; i < 1568; i += 256){
        int r = i / 392, rem = i - r*392;        // 392 uint4 per padded row
        int px = rem >> 2, slot = rem & 3;
        int s = (px & 3) ^ ((px >> 2) & 3);
        *(uint4*)(Bbc + (size_t)r*6272 + (size_t)px*64 + ((slot ^ s)<<4)) = src[i];
      }
    } else {
      // stage from padded bf16 dZq with fused normalize + leaky-relu
      const uint4* src = (const uint4*)(dzq_in + (size_t)(b*2 + ch)*PLANE
                                              + (size_t)y0*PX*ICH);
      for (int i = tid; i < 1568; i += 256){
        int r = i / 392, rem = i - r*392;
        int px = rem >> 2, slot = rem & 3;
        int s = (px & 3) ^ ((px >> 2) & 3);
        int ry = y0 + r;                  // padded row index (0 and 97 are pads)
        uint4 v = src[i];
        union { uint4 v; unsigned short u[8]; } o;
        if (ry >= 1 && ry <= 96 && px >= 1 && px <= 96){
          const unsigned short* hv = (const unsigned short*)&v;
#pragma unroll
          for (int k=0;k<8;k++){
            float2 mr = stat_s[ch*32 + slot*8 + k];
            float f = (float)*(const bf16*)&hv[k];
            float val = (f - mr.x)*mr.y;
            val = (val >= 0.f) ? val : 0.2f*val;
            bf16 hh = (bf16)val;
            o.u[k] = *(unsigned short*)&hh;
          }
        } else {
          o.v = make_uint4(0u,0u,0u,0u);
        }
        *(uint4*)(Bbc + (size_t)r*6272 + (size_t)px*64 + ((slot ^ s)<<4)) = o.v;
      }
    }
    for (int tg = 0; tg < 3; tg++){       // tap row groups (ky = tg)
      __syncthreads();
      { // stage 3 taps x 2 reps x 32 oc (this block's half) x 32 ic, swizzled
        const uint4* srcA = (const uint4*)(apk + (size_t)ch*36864);
        for (int i = tid; i < 768; i += 256){
          int chunk = i >> 7, j = i & 127;       // chunk = tap_r*2+rep, 128 u4/chunk
          int tap_r = chunk >> 1, rep = chunk & 1;
          int oc = j >> 2, slot = j & 3;
          int s = (oc & 3) ^ ((oc >> 2) & 3);
          *(uint4*)(Abc + (size_t)chunk*2048 + (size_t)oc*64 + ((slot ^ s)<<4))
              = srcA[((size_t)((tg*3 + tap_r)*2 + rep))*256 + h*128 + j];
        }
      }
      __syncthreads();
#pragma unroll
      for (int tj = 0; tj < 3; tj++){     // kx = tj
        const int ky = tg, kx = tj;
        bf16x8 Ah[2], Al[2];
#pragma unroll
        for (int mt=0;mt<2;mt++){
          int oc32 = mt*16 + n16;
          int sA = (oc32 & 3) ^ ((oc32 >> 2) & 3);
          Ah[mt] = *(const bf16x8*)(Abc + (size_t)(tj*2 + 0)*2048 + (size_t)oc32*64 + ((q ^ sA)<<4));
          Al[mt] = *(const bf16x8*)(Abc + (size_t)(tj*2 + 1)*2048 + (size_t)oc32*64 + ((q ^ sA)<<4));
        }
        bf16x8 Bf[3];
#pragma unroll
        for (int nt=0;nt<3;nt++){
          int px = wcol + nt*16 + n16 + kx;
          int sB = (px & 3) ^ ((px >> 2) & 3);
          Bf[nt] = *(const bf16x8*)(Bbc + (size_t)(wr + ky)*6272 + (size_t)px*64 + ((q ^ sB)<<4));
        }
#pragma unroll
        for (int nt=0;nt<3;nt++)
#pragma unroll
          for (int mt=0;mt<2;mt++)
            acc[mt][nt] = __builtin_amdgcn_mfma_f32_16x16x32_bf16(Ah[mt], Bf[nt], acc[mt][nt], 0,0,0);
#pragma unroll
        for (int nt=0;nt<3;nt++)
#pragma unroll
          for (int mt=0;mt<2;mt++)
            acc[mt][nt] = __builtin_amdgcn_mfma_f32_16x16x32_bf16(Al[mt], Bf[nt], acc[mt][nt], 0,0,0);
      }
    }
  }

  // ---------------- epilogue ----------------
  if (MODE >= 1){   // yv = -acc (+X at l=7) (+X0 at l=0)
#pragma unroll
    for (int mt=0;mt<2;mt++)
#pragma unroll
      for (int nt=0;nt<3;nt++){
        const int x = wcol + nt*16 + n16;
#pragma unroll
        for (int r=0;r<4;r++){
          const int oc = h*32 + mt*16 + q*4 + r;
          float v = -acc[mt][nt][r];
          if (Xadd)  v += Xadd[(((size_t)b*64 + oc)*96 + yg)*96 + x];
          if (X0add) v += X0add[((size_t)oc*96 + yg)*96 + x];
          acc[mt][nt][r] = v;
        }
      }
  }
  if (MODE == 2){   // final iter: fused forward scan, fp32 NCHW stores
#pragma unroll
    for (int mt=0;mt<2;mt++)
#pragma unroll
      for (int nt=0;nt<3;nt++){
        const int x = wcol + nt*16 + n16;
#pragma unroll
        for (int r=0;r<4;r++){
          const int oc = h*32 + mt*16 + q*4 + r;
          size_t idx = (((size_t)b*64 + oc)*96 + yg)*96 + x;
          float prev = (b_i != 0.f) ? zb_prev[idx] : 0.f;
          zb_out[idx] = a_i*(b_i*prev + acc[mt][nt][r]);
        }
      }
    return;
  }

  __syncthreads();                        // all waves done with Bbc/Abc
  float* T = (float*)smem + w*1584;       // per-wave 48 x 33 fp32 transpose tile
#pragma unroll
  for (int mt2=0; mt2<2; mt2++)
#pragma unroll
    for (int nt=0;nt<3;nt++)
#pragma unroll
      for (int r=0;r<4;r++)
        T[(nt*16 + n16)*33 + mt2*16 + q*4 + r] = acc[mt2][nt][r];

  float s4[4] = {0.f,0.f,0.f,0.f};        // MODE 0: per-lane stats (acc now dead)
  float q4[4] = {0.f,0.f,0.f,0.f};
  for (int f = lane; f < 384; f += 64){
    int px = f>>3, c4 = (f&7)*4;
    float vv[4];
#pragma unroll
    for (int k=0;k<4;k++) vv[k] = T[px*33 + c4 + k];
    int x = wcol + px;
    if (MODE == 0){
      // store raw dZ as bf16 into the padded layout (stats stay fp32-exact)
      size_t off = ((size_t)(b*2 + h)*PY + (yg+1))*(size_t)PX*ICH
                 + (size_t)(x+1)*ICH + c4;
      union { uint2 v; unsigned short u[4]; } oo;
#pragma unroll
      for (int k=0;k<4;k++){
        bf16 hh = (bf16)vv[k];
        oo.u[k] = *(unsigned short*)&hh;
        s4[k] += vv[k]; q4[k] += vv[k]*vv[k];
      }
      *(uint2*)(dzq_out + off) = oo.v;
    } else {
      size_t off = ((size_t)(b*2 + h)*PY + (yg+1))*(size_t)PX*ICH
                 + (size_t)(x+1)*ICH + c4;
      uint2 pv = *(const uint2*)(yfq_prev + off);
      bf16* ph = (bf16*)&pv;
      union { uint2 v; unsigned short u[4]; } o;
#pragma unroll
      for (int k=0;k<4;k++){
        float yf = a_i*(b_i*(float)ph[k] + vv[k]);
        bf16 hh = (bf16)yf;
        o.u[k] = *(unsigned short*)&hh;
      }
      *(uint2*)(yfq_out + off) = o.v;
    }
  }

  if (MODE == 0){
    // lanes sharing (lane&7) hold partials for the same 4 channels: xor 8/16/32
#pragma unroll
    for (int st = 8; st < 64; st <<= 1)
#pragma unroll
      for (int k=0;k<4;k++){
        s4[k] += __shfl_xor(s4[k], st, 64);
        q4[k] += __shfl_xor(q4[k], st, 64);
      }
    if (lane < 8){
#pragma unroll
      for (int k=0;k<4;k++){
        sred[w][lane*4 + k] = s4[k];
        qred[w][lane*4 + k] = q4[k];
      }
    }
    __syncthreads();
    if (tid < 32){
      float ss = sred[0][tid] + sred[1][tid] + sred[2][tid] + sred[3][tid];
      float qq = qred[0][tid] + qred[1][tid] + qred[2][tid] + qred[3][tid];
      size_t base = ((size_t)b*64 + h*32 + tid)*STAT_STRIDE;
      atomicAdd(&accstat[base], ss);
      atomicAdd(&accstat[base + 16], qq);
    }
  }
}

// ---------------------------------------------------------------------------
// R12: persistent mega-kernel. One dispatch replaces 24x(conv<0>,conv<1/2>)
// + 3 back-scans (~50 dispatch gaps of ~8us each). Grid barriers only where a
// true grid-wide dependency exists:
//  * A(l)->B(l): instance-norm stats (1 gsync per layer-step)
//  * B(l)->A(l+1): NONE needed — dZq is ping-ponged (2 slots), and the gsync
//    after A(l+1) orders B(l-1) reads vs A(l+1) writes of the same slot.
//  * iteration end: gsync, in-place back scan, gsync.
__global__ __launch_bounds__(256, 3) void fused_all(
    bf16* __restrict__ Zq, bf16* __restrict__ dZq2,
    const bf16* __restrict__ apf, const bf16* __restrict__ apb,
    float* __restrict__ statacc,
    const float* __restrict__ X, const float* __restrict__ X0,
    float* __restrict__ zbase, float* __restrict__ out0,
    unsigned* __restrict__ bar, unsigned* __restrict__ gen)
{
  __shared__ __align__(16) char smem[25088 + 12288];
  __shared__ float sred[4][32];
  __shared__ float qred[4][32];
  __shared__ float2 stat_s[64];

  // initial backward scan Yf(it=0) -> Z (init_yf_t wrote Yf before us)
  back_scan_phase(Zq);
  gsync(bar, gen);

  for (int it = 1; it <= 3; ++it){
    for (int l = 0; l < NL; ++l){
      float* accs = statacc + (size_t)((it-1)*NL + l)*STAT_SLOT;
      bf16* dq = dZq2 + (size_t)(l & 1)*PL;
      conv_body<0>(smem, sred, qred, stat_s,
                   Zq + (size_t)l*PL, nullptr, apf + (size_t)l*APK_L,
                   dq, accs, nullptr, nullptr, nullptr, nullptr,
                   nullptr, nullptr, 0.f, 0.f);
      gsync(bar, gen);
      float ai = a_of(l), bi = b_of(l);
      const float* Xa  = (l==NL-1) ? X  : nullptr;
      const float* X0a = (l==0)    ? X0 : nullptr;
      if (it < 3)
        conv_body<1>(smem, sred, qred, stat_s,
                     nullptr, dq, apb + (size_t)l*APK_L,
                     nullptr, accs,
                     Zq + (size_t)l*PL, Zq + (size_t)(l>0?l-1:0)*PL,
                     nullptr, nullptr, Xa, X0a, ai, bi);
      else
        conv_body<2>(smem, sred, qred, stat_s,
                     nullptr, dq, apb + (size_t)l*APK_L,
                     nullptr, accs, nullptr, nullptr,
                     zbase + (size_t)l*LSTRIDE, zbase + (size_t)(l>0?l-1:0)*LSTRIDE,
                     Xa, X0a, ai, bi);
    }
    gsync(bar, gen);
    if (it < 3){
      back_scan_phase(Zq);
      gsync(bar, gen);
    } else {
      back_scan_final_phase(zbase, out0);
    }
  }
}

// ---------------------------------------------------------------------------
extern "C" void kernel_launch(void* const* d_in, const int* in_sizes, int n_in,
                              void* d_out, int out_size, void* d_ws, size_t ws_size,
                              hipStream_t stream) {
  const float* X  = (const float*)d_in[0];
  const float* K  = (const float*)d_in[1];
  const float* X0 = (const float*)d_in[2];

  float* out0  = (float*)d_out;
  float* zbase = out0 + LSTRIDE;

  char* ws = (char*)d_ws;
  float*    statacc = (float*)ws;                       // 24 x 64KB padded slots
  unsigned* syncv   = (unsigned*)(ws + 24*STAT_SLOT*4); // bar @+0, gen @+64B
  bf16*     apf     = (bf16*)(ws + 24*STAT_SLOT*4 + 256);
  bf16*     apb     = apf + (size_t)NL*APK_L;
  bf16*     Zq      = apb + (size_t)NL*APK_L;           // 8*PL (doubles as Yfq)
  bf16*     dZq2    = Zq + (size_t)NL*PL;               // 2*PL ping-pong

  // zero stats slots + grid-barrier state (inside graph -> clean each replay)
  hipMemsetAsync(statacc, 0, 24*STAT_SLOT*4 + 256, stream);
  hipMemsetAsync(Zq, 0, (size_t)NL*PL*2, stream);       // zero pads

  pack_weights<<<(NL*9*4096 + 255)/256, 256, 0, stream>>>(K, apf, apb);
  init_yf_t<<<dim3(HC, BB), 256, 0, stream>>>(X, X0, Zq);

  fused_all<<<NBLK, 256, 0, stream>>>(
      Zq, dZq2, apf, apb, statacc, X, X0, zbase, out0,
      syncv, syncv + 16);
}

// Round 13
// 3333.098 us; speedup vs baseline: 1.8155x; 1.8155x over previous
//
#include <hip/hip_runtime.h>
#include <math.h>

// ---------------- problem constants ----------------
#define HC 96
#define WC 96
#define CCH 64
#define BB 8
#define NL 8
#define IMG (HC*WC)                 // 9216
#define LSTRIDE (BB*CCH*IMG)        // 4,718,592
#define EPS 1e-5f

// padded-chunked NHWC bf16 layout: [b][ch2][y:98][x:98][ic:32]
#define PY 98
#define PX 98
#define ICH 32
#define PLANE (PY*PX*ICH)           // 307,328
#define PL (BB*2*PLANE)             // 4,917,248 els per layer tensor
#define APK_L (2*9*2*64*32)         // 73,728 els per layer per direction

// padded stats layout: per (b,oc) a 128B slot; s at +0, s2 at +16 floats.
#define STAT_STRIDE 32              // floats per (b,oc) slot
#define STAT_SLOT (512*STAT_STRIDE) // floats per layer-step slot (64 KB)

#define NBLK 768                    // 3 blocks/CU x 256 CUs, exact residency
#define GRPBLK 96                   // blocks per batch-group (48 rowg x 2 h)

typedef __bf16 bf16;
typedef bf16 bf16x8 __attribute__((ext_vector_type(8)));
typedef float f32x4 __attribute__((ext_vector_type(4)));

__device__ __forceinline__ float a_of(int i){ return sqrtf((i+1.f)/(i+2.f)); }
__device__ __forceinline__ float b_of(int i){ return sqrtf((float)i/(float)(i+1)); }

// ---------------------------------------------------------------------------
// Per-group (96-block) barrier, NO RMW: arrival = release-store to own slot
// (96 parallel stores, no line serialization — R12's single-line fetch_add
// cost ~150us/barrier from 768 serialized RMWs); master (gi==0) sweeps the
// 96 slots with relaxed loads (pipelined, ~1-2us), full-fences, bumps gen;
// waiters spin on gen (read-shared line). threadfence = full device-scope
// fence pairs the relaxed atomics (fence-based synchronization), same
// coherence mechanics R12 proved correct (absmax passed).
__device__ __forceinline__ void group_sync(unsigned* slots, unsigned* gen,
                                           int gi, unsigned ph){
  __syncthreads();
  if (threadIdx.x == 0){
    __threadfence();
    __hip_atomic_store(&slots[gi], ph, __ATOMIC_RELAXED, __HIP_MEMORY_SCOPE_AGENT);
    if (gi == 0){
      for (;;){
        bool all = true;
        for (int k = 0; k < GRPBLK; ++k){
          unsigned v = __hip_atomic_load(&slots[k], __ATOMIC_RELAXED,
                                         __HIP_MEMORY_SCOPE_AGENT);
          all &= (v >= ph);
        }
        if (all) break;
        __builtin_amdgcn_s_sleep(1);
      }
      __threadfence();
      __hip_atomic_store(gen, ph, __ATOMIC_RELAXED, __HIP_MEMORY_SCOPE_AGENT);
    } else {
      while (__hip_atomic_load(gen, __ATOMIC_RELAXED,
                               __HIP_MEMORY_SCOPE_AGENT) < ph){
        __builtin_amdgcn_s_sleep(1);
      }
    }
    __threadfence();
  }
  __syncthreads();
}

// ---------------------------------------------------------------------------
// Split weights into hi/lo bf16 planes, frag-friendly layout:
// apX[l][ch][tap][rep][oc64][ic32]. fwd: K[l][oc][ic][tap]; bwd: K[l][ic][oc][8-tap].
__global__ void pack_weights(const float* __restrict__ K,
                             bf16* __restrict__ apf, bf16* __restrict__ apb){
  int idx = blockIdx.x*256 + threadIdx.x;          // NL*9*64*64
  if (idx >= NL*9*64*64) return;
  int ic = idx & 63, oc = (idx>>6) & 63;
  int tap = (idx>>12) % 9, l = idx/(4096*9);
  float wf = K[(((size_t)l*64 + oc)*64 + ic)*9 + tap];
  float wb = K[(((size_t)l*64 + ic)*64 + oc)*9 + (8-tap)];
  int ch = ic>>5, ic5 = ic&31;
  size_t base = (size_t)l*APK_L + ((size_t)((ch*9 + tap)*2)*64 + oc)*32 + ic5;
  bf16 fh = (bf16)wf;
  apf[base] = fh; apf[base + 64*32] = (bf16)(wf - (float)fh);
  bf16 bh = (bf16)wb;
  apb[base] = bh; apb[base + 64*32] = (bf16)(wb - (float)bh);
}

// ---------------------------------------------------------------------------
// Fix-iter 0 constant-folded: Yf closed form from X, X0; writes padded NHWC bf16.
__global__ __launch_bounds__(256) void init_yf_t(const float* __restrict__ X,
                                                 const float* __restrict__ X0,
                                                 bf16* __restrict__ yfq){
  __shared__ float LX[64][97];
  __shared__ float L0[64][97];
  int b = blockIdx.y, y = blockIdx.x;
  for (int i = threadIdx.x; i < 64*96; i += 256){
    int c = i/96, x = i%96;
    LX[c][x] = X[(((size_t)b*64 + c)*96 + y)*96 + x];
    L0[c][x] = X0[((size_t)c*96 + y)*96 + x];
  }
  __syncthreads();
  for (int j = threadIdx.x; j < 96*64; j += 256){
    int x = j>>6, c = j&63;
    float xv = LX[c][x], x0v = L0[c][x];
    size_t eoff = ((size_t)(b*2 + (c>>5))*PY + (y+1))*(size_t)PX*ICH
                + (size_t)(x+1)*ICH + (c&31);
    float yf = 0.f;
#pragma unroll
    for (int i = 0; i < NL; i++){
      float yv = (i==0 ? x0v : 0.f) + (i==NL-1 ? xv : 0.f);
      yf = a_of(i)*(b_of(i)*yf + yv);
      yfq[(size_t)i*PL + eoff] = (bf16)yf;
    }
  }
}

// ---------------------------------------------------------------------------
// Backward scan over this group's batch-b slice of padded bf16 Yf->Z in place.
__device__ void back_scan_b(bf16* __restrict__ buf, int b, int gi){
  const size_t n8 = (size_t)2*PLANE/8;           // 76,832 uint4 per b-slice
  for (size_t i8 = (size_t)gi*256 + threadIdx.x; i8 < n8;
       i8 += (size_t)GRPBLK*256){
    size_t base = (size_t)b*2*PLANE + i8*8;
    float c[8];
#pragma unroll
    for (int e=0;e<8;e++) c[e]=0.f;
#pragma unroll
    for (int l = NL-1; l >= 0; l--){
      float al = a_of(l);
      uint4 v = *(const uint4*)(buf + (size_t)l*PL + base);
      bf16* hp = (bf16*)&v;
      uint4 o; bf16* ho = (bf16*)&o;
#pragma unroll
      for (int e=0;e<8;e++){
        float z = al*(al*c[e] + (float)hp[e]);
        ho[e] = (bf16)z; c[e] = z;
      }
      *(uint4*)(buf + (size_t)l*PL + base) = o;
    }
  }
}

// Final backward scan on this b's NCHW slice: zbase in place, out0 = Z[7].
__device__ void back_scan_final_b(float* __restrict__ zbase,
                                  float* __restrict__ out0, int b, int gi){
  const size_t nb = (size_t)64*IMG;              // 589,824 floats per b
  const size_t boff = (size_t)b*64*IMG;
  for (size_t idx = (size_t)gi*256 + threadIdx.x; idx < nb;
       idx += (size_t)GRPBLK*256){
    float c = 0.f;
#pragma unroll
    for (int i = NL-1; i >= 0; i--){
      float ai = a_of(i);
      float z = ai*(ai*c + zbase[(size_t)i*LSTRIDE + boff + idx]);
      zbase[(size_t)i*LSTRIDE + boff + idx] = z;
      if (i == NL-1) out0[boff + idx] = z;
      c = z;
    }
  }
}

// ---------------------------------------------------------------------------
// R11's conv_mfma verbatim as a device function (explicit rowg/b/h).
// MODE 0: in=Zq[l] -> dzq_out (padded bf16, LDS transpose) + fused stats
// MODE 1: in=dzq_in+stats; yv=-acc(+X/+X0); yf=a*(b*prev+yv) -> yfq_out
// MODE 2: same math fp32, direct NCHW stores to zb_out (final iteration)
template<int MODE>
__device__ void conv_body(char* smem, float (*sred)[32], float (*qred)[32],
    float2* stat_s, int rowg, int b, int h,
    const bf16* __restrict__ inq, const bf16* __restrict__ dzq_in,
    const bf16* __restrict__ apk,
    bf16* __restrict__ dzq_out, float* __restrict__ accstat,
    bf16* __restrict__ yfq_out, const bf16* __restrict__ yfq_prev,
    float* __restrict__ zb_out, const float* __restrict__ zb_prev,
    const float* __restrict__ Xadd, const float* __restrict__ X0add,
    float a_i, float b_i)
{
  char* Bbc = smem;                        // [4 rows][98 px][32 ic] bf16, swizzled
  char* Abc = smem + 25088;                // [3 taps][2 rep][32 oc][32 ic] bf16, swz

  const int y0 = rowg*2;
  const int tid = threadIdx.x;
  const int w = tid>>6, lane = tid&63;
  const int n16 = lane&15, q = lane>>4;
  const int wr = w>>1, wcol = (w&1)*48;
  const int yg = y0 + wr;

  if (MODE >= 1){   // finalize instance-norm stats for this b (padded slot)
    if (tid < 64){
      float s  = accstat[((size_t)b*64 + tid)*STAT_STRIDE];
      float s2 = accstat[((size_t)b*64 + tid)*STAT_STRIDE + 16];
      float m = s*(1.f/IMG);
      float vv = s2*(1.f/IMG) - m*m;
      if (vv < 0.f) vv = 0.f;
      stat_s[tid] = make_float2(m, rsqrtf(vv + EPS));
    }
    __syncthreads();
  }

  f32x4 acc[2][3];
#pragma unroll
  for (int a=0;a<2;a++)
#pragma unroll
    for (int c=0;c<3;c++){ f32x4 z = {0.f,0.f,0.f,0.f}; acc[a][c] = z; }

  for (int ch = 0; ch < 2; ch++){
    __syncthreads();
    if (MODE == 0){
      // stage 4 padded rows x 98 cols x 32 ic, swizzled 16B slots (raw bf16)
      const uint4* src = (const uint4*)(inq + (size_t)(b*2 + ch)*PLANE
                                            + (size_t)y0*PX*ICH);
      for (int i = tid; i < 1568; i += 256){
        int r = i / 392, rem = i - r*392;        // 392 uint4 per padded row
        int px = rem >> 2, slot = rem & 3;
        int s = (px & 3) ^ ((px >> 2) & 3);
        *(uint4*)(Bbc + (size_t)r*6272 + (size_t)px*64 + ((slot ^ s)<<4)) = src[i];
      }
    } else {
      // stage from padded bf16 dZq with fused normalize + leaky-relu
      const uint4* src = (const uint4*)(dzq_in + (size_t)(b*2 + ch)*PLANE
                                              + (size_t)y0*PX*ICH);
      for (int i = tid; i < 1568; i += 256){
        int r = i / 392, rem = i - r*392;
        int px = rem >> 2, slot = rem & 3;
        int s = (px & 3) ^ ((px >> 2) & 3);
        int ry = y0 + r;                  // padded row index (0 and 97 are pads)
        uint4 v = src[i];
        union { uint4 v; unsigned short u[8]; } o;
        if (ry >= 1 && ry <= 96 && px >= 1 && px <= 96){
          const unsigned short* hv = (const unsigned short*)&v;
#pragma unroll
          for (int k=0;k<8;k++){
            float2 mr = stat_s[ch*32 + slot*8 + k];
            float f = (float)*(const bf16*)&hv[k];
            float val = (f - mr.x)*mr.y;
            val = (val >= 0.f) ? val : 0.2f*val;
            bf16 hh = (bf16)val;
            o.u[k] = *(unsigned short*)&hh;
          }
        } else {
          o.v = make_uint4(0u,0u,0u,0u);
        }
        *(uint4*)(Bbc + (size_t)r*6272 + (size_t)px*64 + ((slot ^ s)<<4)) = o.v;
      }
    }
    for (int tg = 0; tg < 3; tg++){       // tap row groups (ky = tg)
      __syncthreads();
      { // stage 3 taps x 2 reps x 32 oc (this block's half) x 32 ic, swizzled
        const uint4* srcA = (const uint4*)(apk + (size_t)ch*36864);
        for (int i = tid; i < 768; i += 256){
          int chunk = i >> 7, j = i & 127;       // chunk = tap_r*2+rep, 128 u4/chunk
          int tap_r = chunk >> 1, rep = chunk & 1;
          int oc = j >> 2, slot = j & 3;
          int s = (oc & 3) ^ ((oc >> 2) & 3);
          *(uint4*)(Abc + (size_t)chunk*2048 + (size_t)oc*64 + ((slot ^ s)<<4))
              = srcA[((size_t)((tg*3 + tap_r)*2 + rep))*256 + h*128 + j];
        }
      }
      __syncthreads();
#pragma unroll
      for (int tj = 0; tj < 3; tj++){     // kx = tj
        const int ky = tg, kx = tj;
        bf16x8 Ah[2], Al[2];
#pragma unroll
        for (int mt=0;mt<2;mt++){
          int oc32 = mt*16 + n16;
          int sA = (oc32 & 3) ^ ((oc32 >> 2) & 3);
          Ah[mt] = *(const bf16x8*)(Abc + (size_t)(tj*2 + 0)*2048 + (size_t)oc32*64 + ((q ^ sA)<<4));
          Al[mt] = *(const bf16x8*)(Abc + (size_t)(tj*2 + 1)*2048 + (size_t)oc32*64 + ((q ^ sA)<<4));
        }
        bf16x8 Bf[3];
#pragma unroll
        for (int nt=0;nt<3;nt++){
          int px = wcol + nt*16 + n16 + kx;
          int sB = (px & 3) ^ ((px >> 2) & 3);
          Bf[nt] = *(const bf16x8*)(Bbc + (size_t)(wr + ky)*6272 + (size_t)px*64 + ((q ^ sB)<<4));
        }
#pragma unroll
        for (int nt=0;nt<3;nt++)
#pragma unroll
          for (int mt=0;mt<2;mt++)
            acc[mt][nt] = __builtin_amdgcn_mfma_f32_16x16x32_bf16(Ah[mt], Bf[nt], acc[mt][nt], 0,0,0);
#pragma unroll
        for (int nt=0;nt<3;nt++)
#pragma unroll
          for (int mt=0;mt<2;mt++)
            acc[mt][nt] = __builtin_amdgcn_mfma_f32_16x16x32_bf16(Al[mt], Bf[nt], acc[mt][nt], 0,0,0);
      }
    }
  }

  // ---------------- epilogue ----------------
  if (MODE >= 1){   // yv = -acc (+X at l=7) (+X0 at l=0)
#pragma unroll
    for (int mt=0;mt<2;mt++)
#pragma unroll
      for (int nt=0;nt<3;nt++){
        const int x = wcol + nt*16 + n16;
#pragma unroll
        for (int r=0;r<4;r++){
          const int oc = h*32 + mt*16 + q*4 + r;
          float v = -acc[mt][nt][r];
          if (Xadd)  v += Xadd[(((size_t)b*64 + oc)*96 + yg)*96 + x];
          if (X0add) v += X0add[((size_t)oc*96 + yg)*96 + x];
          acc[mt][nt][r] = v;
        }
      }
  }
  if (MODE == 2){   // final iter: fused forward scan, fp32 NCHW stores
#pragma unroll
    for (int mt=0;mt<2;mt++)
#pragma unroll
      for (int nt=0;nt<3;nt++){
        const int x = wcol + nt*16 + n16;
#pragma unroll
        for (int r=0;r<4;r++){
          const int oc = h*32 + mt*16 + q*4 + r;
          size_t idx = (((size_t)b*64 + oc)*96 + yg)*96 + x;
          float prev = (b_i != 0.f) ? zb_prev[idx] : 0.f;
          zb_out[idx] = a_i*(b_i*prev + acc[mt][nt][r]);
        }
      }
    return;
  }

  __syncthreads();                        // all waves done with Bbc/Abc
  float* T = (float*)smem + w*1584;       // per-wave 48 x 33 fp32 transpose tile
#pragma unroll
  for (int mt2=0; mt2<2; mt2++)
#pragma unroll
    for (int nt=0;nt<3;nt++)
#pragma unroll
      for (int r=0;r<4;r++)
        T[(nt*16 + n16)*33 + mt2*16 + q*4 + r] = acc[mt2][nt][r];

  float s4[4] = {0.f,0.f,0.f,0.f};        // MODE 0: per-lane stats (acc now dead)
  float q4[4] = {0.f,0.f,0.f,0.f};
  for (int f = lane; f < 384; f += 64){
    int px = f>>3, c4 = (f&7)*4;
    float vv[4];
#pragma unroll
    for (int k=0;k<4;k++) vv[k] = T[px*33 + c4 + k];
    int x = wcol + px;
    if (MODE == 0){
      // store raw dZ as bf16 into the padded layout (stats stay fp32-exact)
      size_t off = ((size_t)(b*2 + h)*PY + (yg+1))*(size_t)PX*ICH
                 + (size_t)(x+1)*ICH + c4;
      union { uint2 v; unsigned short u[4]; } oo;
#pragma unroll
      for (int k=0;k<4;k++){
        bf16 hh = (bf16)vv[k];
        oo.u[k] = *(unsigned short*)&hh;
        s4[k] += vv[k]; q4[k] += vv[k]*vv[k];
      }
      *(uint2*)(dzq_out + off) = oo.v;
    } else {
      size_t off = ((size_t)(b*2 + h)*PY + (yg+1))*(size_t)PX*ICH
                 + (size_t)(x+1)*ICH + c4;
      uint2 pv = *(const uint2*)(yfq_prev + off);
      bf16* ph = (bf16*)&pv;
      union { uint2 v; unsigned short u[4]; } o;
#pragma unroll
      for (int k=0;k<4;k++){
        float yf = a_i*(b_i*(float)ph[k] + vv[k]);
        bf16 hh = (bf16)yf;
        o.u[k] = *(unsigned short*)&hh;
      }
      *(uint2*)(yfq_out + off) = o.v;
    }
  }

  if (MODE == 0){
    // lanes sharing (lane&7) hold partials for the same 4 channels: xor 8/16/32
#pragma unroll
    for (int st = 8; st < 64; st <<= 1)
#pragma unroll
      for (int k=0;k<4;k++){
        s4[k] += __shfl_xor(s4[k], st, 64);
        q4[k] += __shfl_xor(q4[k], st, 64);
      }
    if (lane < 8){
#pragma unroll
      for (int k=0;k<4;k++){
        sred[w][lane*4 + k] = s4[k];
        qred[w][lane*4 + k] = q4[k];
      }
    }
    __syncthreads();
    if (tid < 32){
      float ss = sred[0][tid] + sred[1][tid] + sred[2][tid] + sred[3][tid];
      float qq = qred[0][tid] + qred[1][tid] + qred[2][tid] + qred[3][tid];
      size_t base = ((size_t)b*64 + h*32 + tid)*STAT_STRIDE;
      atomicAdd(&accstat[base], ss);
      atomicAdd(&accstat[base + 16], qq);
    }
  }
}

// ---------------------------------------------------------------------------
// R13: persistent kernel, 8 INDEPENDENT batch-groups of 96 blocks. All deps
// (stats, conv halos, scans, zbase) are b-local, so barriers are group-local:
// ~30 per group at ~2-4us (slot-store + master-sweep, no RMW serialization).
// Groups drift freely — straggler tails overlap across groups.
__global__ __launch_bounds__(256, 3) void fused_all(
    bf16* __restrict__ Zq, bf16* __restrict__ dZq2,
    const bf16* __restrict__ apf, const bf16* __restrict__ apb,
    float* __restrict__ statacc,
    const float* __restrict__ X, const float* __restrict__ X0,
    float* __restrict__ zbase, float* __restrict__ out0,
    unsigned* __restrict__ sync)
{
  __shared__ __align__(16) char smem[25088 + 12288];
  __shared__ float sred[4][32];
  __shared__ float qred[4][32];
  __shared__ float2 stat_s[64];

  const int gb = blockIdx.x / GRPBLK;     // batch group (= b)
  const int gi = blockIdx.x % GRPBLK;     // index within group
  const int rowg = gi % 48, h = gi / 48;
  unsigned* gslots = sync + (size_t)gb*256;    // 96 slots
  unsigned* ggen   = gslots + 128;             // own cache line
  unsigned ph = 0;

  // initial backward scan Yf(it=0) -> Z for this b (init_yf_t ran before us)
  back_scan_b(Zq, gb, gi);
  group_sync(gslots, ggen, gi, ++ph);

  for (int it = 1; it <= 3; ++it){
    for (int l = 0; l < NL; ++l){
      float* accs = statacc + (size_t)((it-1)*NL + l)*STAT_SLOT;
      bf16* dq = dZq2 + (size_t)(l & 1)*PL;
      conv_body<0>(smem, sred, qred, stat_s, rowg, gb, h,
                   Zq + (size_t)l*PL, nullptr, apf + (size_t)l*APK_L,
                   dq, accs, nullptr, nullptr, nullptr, nullptr,
                   nullptr, nullptr, 0.f, 0.f);
      group_sync(gslots, ggen, gi, ++ph);      // stats + dZq halo ready
      float ai = a_of(l), bi = b_of(l);
      const float* Xa  = (l==NL-1) ? X  : nullptr;
      const float* X0a = (l==0)    ? X0 : nullptr;
      if (it < 3)
        conv_body<1>(smem, sred, qred, stat_s, rowg, gb, h,
                     nullptr, dq, apb + (size_t)l*APK_L,
                     nullptr, accs,
                     Zq + (size_t)l*PL, Zq + (size_t)(l>0?l-1:0)*PL,
                     nullptr, nullptr, Xa, X0a, ai, bi);
      else
        conv_body<2>(smem, sred, qred, stat_s, rowg, gb, h,
                     nullptr, dq, apb + (size_t)l*APK_L,
                     nullptr, accs, nullptr, nullptr,
                     zbase + (size_t)l*LSTRIDE, zbase + (size_t)(l>0?l-1:0)*LSTRIDE,
                     Xa, X0a, ai, bi);
      // no barrier B(l)->A(l+1): disjoint tensors (dZq ping-pong; Zq layers)
    }
    group_sync(gslots, ggen, gi, ++ph);        // B(7) writes done
    if (it < 3){
      back_scan_b(Zq, gb, gi);
      group_sync(gslots, ggen, gi, ++ph);      // scan writes done
    } else {
      back_scan_final_b(zbase, out0, gb, gi);
    }
  }
}

// ---------------------------------------------------------------------------
extern "C" void kernel_launch(void* const* d_in, const int* in_sizes, int n_in,
                              void* d_out, int out_size, void* d_ws, size_t ws_size,
                              hipStream_t stream) {
  const float* X  = (const float*)d_in[0];
  const float* K  = (const float*)d_in[1];
  const float* X0 = (const float*)d_in[2];

  float* out0  = (float*)d_out;
  float* zbase = out0 + LSTRIDE;

  char* ws = (char*)d_ws;
  float*    statacc = (float*)ws;                       // 24 x 64KB padded slots
  unsigned* syncv   = (unsigned*)(ws + 24*STAT_SLOT*4); // 8 groups x 1KB
  bf16*     apf     = (bf16*)(ws + 24*STAT_SLOT*4 + 8192);
  bf16*     apb     = apf + (size_t)NL*APK_L;
  bf16*     Zq      = apb + (size_t)NL*APK_L;           // 8*PL (doubles as Yfq)
  bf16*     dZq2    = Zq + (size_t)NL*PL;               // 2*PL ping-pong

  // zero stats slots + barrier state (inside graph -> clean each replay)
  hipMemsetAsync(statacc, 0, 24*STAT_SLOT*4 + 8192, stream);
  hipMemsetAsync(Zq, 0, (size_t)NL*PL*2, stream);       // zero pads

  pack_weights<<<(NL*9*4096 + 255)/256, 256, 0, stream>>>(K, apf, apb);
  init_yf_t<<<dim3(HC, BB), 256, 0, stream>>>(X, X0, Zq);

  fused_all<<<NBLK, 256, 0, stream>>>(
      Zq, dZq2, apf, apb, statacc, X, X0, zbase, out0, syncv);
}

// Round 14
// 2864.899 us; speedup vs baseline: 2.1122x; 1.1634x over previous
//
#include <hip/hip_runtime.h>
#include <math.h>

// ---------------- problem constants ----------------
#define HC 96
#define WC 96
#define CCH 64
#define BB 8
#define NL 8
#define IMG (HC*WC)                 // 9216
#define LSTRIDE (BB*CCH*IMG)        // 4,718,592
#define EPS 1e-5f

// padded-chunked NHWC bf16 layout: [b][ch2][y:98][x:98][ic:32]
#define PY 98
#define PX 98
#define ICH 32
#define PLANE (PY*PX*ICH)           // 307,328
#define PL (BB*2*PLANE)             // 4,917,248 els per layer tensor
#define APK_L (2*9*2*64*32)         // 73,728 els per layer per direction

// padded stats layout: per (b,oc) a 128B slot; s at +0, s2 at +16 floats.
#define STAT_STRIDE 32              // floats per (b,oc) slot
#define STAT_SLOT (512*STAT_STRIDE) // floats per layer-step slot (64 KB)

#define NBLK 768                    // 3 blocks/CU x 256 CUs, exact residency
#define GRPBLK 96                   // blocks per batch-group (48 rowg x 2 h)
#define SYNC_GRP_U (GRPBLK*32 + 32) // uints per group: 96 padded slots + gen line

typedef __bf16 bf16;
typedef bf16 bf16x8 __attribute__((ext_vector_type(8)));
typedef float f32x4 __attribute__((ext_vector_type(4)));

__device__ __forceinline__ float a_of(int i){ return sqrtf((i+1.f)/(i+2.f)); }
__device__ __forceinline__ float b_of(int i){ return sqrtf((float)i/(float)(i+1)); }

// ---------------------------------------------------------------------------
// Per-group (96-block) barrier, R14 redesign.
// R13's master swept 96 slots with a SERIAL dependent-load loop (~500ns
// L2-bypassing load + waitcnt each = ~48us/sweep) and arrival slots shared
// cache lines (16 writers/line ping-pong). Fixes:
//  * slots padded to 128B (exclusive line per writer, parallel arrivals)
//  * master polls with THREADS 0..95 IN PARALLEL — one wave-wide load has
//    64 line-fetches in flight; exec-mask re-polls only unsatisfied lanes.
// Fence structure identical to the R12/R13-proven one (absmax passed).
__device__ __forceinline__ void group_sync(unsigned* slots, unsigned* gen,
                                           int gi, unsigned ph){
  __syncthreads();
  if (threadIdx.x == 0){
    __threadfence();
    __hip_atomic_store(&slots[(size_t)gi*32], ph, __ATOMIC_RELAXED,
                       __HIP_MEMORY_SCOPE_AGENT);
  }
  if (gi == 0){
    if (threadIdx.x < GRPBLK){
      while (__hip_atomic_load(&slots[(size_t)threadIdx.x*32],
                               __ATOMIC_RELAXED, __HIP_MEMORY_SCOPE_AGENT) < ph){
        __builtin_amdgcn_s_sleep(1);
      }
    }
    __syncthreads();
    if (threadIdx.x == 0){
      __threadfence();
      __hip_atomic_store(gen, ph, __ATOMIC_RELAXED, __HIP_MEMORY_SCOPE_AGENT);
      __threadfence();
    }
    __syncthreads();
  } else {
    if (threadIdx.x == 0){
      while (__hip_atomic_load(gen, __ATOMIC_RELAXED,
                               __HIP_MEMORY_SCOPE_AGENT) < ph){
        __builtin_amdgcn_s_sleep(1);
      }
      __threadfence();
    }
    __syncthreads();
  }
}

// ---------------------------------------------------------------------------
// Split weights into hi/lo bf16 planes, frag-friendly layout:
// apX[l][ch][tap][rep][oc64][ic32]. fwd: K[l][oc][ic][tap]; bwd: K[l][ic][oc][8-tap].
__global__ void pack_weights(const float* __restrict__ K,
                             bf16* __restrict__ apf, bf16* __restrict__ apb){
  int idx = blockIdx.x*256 + threadIdx.x;          // NL*9*64*64
  if (idx >= NL*9*64*64) return;
  int ic = idx & 63, oc = (idx>>6) & 63;
  int tap = (idx>>12) % 9, l = idx/(4096*9);
  float wf = K[(((size_t)l*64 + oc)*64 + ic)*9 + tap];
  float wb = K[(((size_t)l*64 + ic)*64 + oc)*9 + (8-tap)];
  int ch = ic>>5, ic5 = ic&31;
  size_t base = (size_t)l*APK_L + ((size_t)((ch*9 + tap)*2)*64 + oc)*32 + ic5;
  bf16 fh = (bf16)wf;
  apf[base] = fh; apf[base + 64*32] = (bf16)(wf - (float)fh);
  bf16 bh = (bf16)wb;
  apb[base] = bh; apb[base + 64*32] = (bf16)(wb - (float)bh);
}

// ---------------------------------------------------------------------------
// Fix-iter 0 constant-folded: Yf closed form from X, X0; writes padded NHWC bf16.
__global__ __launch_bounds__(256) void init_yf_t(const float* __restrict__ X,
                                                 const float* __restrict__ X0,
                                                 bf16* __restrict__ yfq){
  __shared__ float LX[64][97];
  __shared__ float L0[64][97];
  int b = blockIdx.y, y = blockIdx.x;
  for (int i = threadIdx.x; i < 64*96; i += 256){
    int c = i/96, x = i%96;
    LX[c][x] = X[(((size_t)b*64 + c)*96 + y)*96 + x];
    L0[c][x] = X0[((size_t)c*96 + y)*96 + x];
  }
  __syncthreads();
  for (int j = threadIdx.x; j < 96*64; j += 256){
    int x = j>>6, c = j&63;
    float xv = LX[c][x], x0v = L0[c][x];
    size_t eoff = ((size_t)(b*2 + (c>>5))*PY + (y+1))*(size_t)PX*ICH
                + (size_t)(x+1)*ICH + (c&31);
    float yf = 0.f;
#pragma unroll
    for (int i = 0; i < NL; i++){
      float yv = (i==0 ? x0v : 0.f) + (i==NL-1 ? xv : 0.f);
      yf = a_of(i)*(b_of(i)*yf + yv);
      yfq[(size_t)i*PL + eoff] = (bf16)yf;
    }
  }
}

// ---------------------------------------------------------------------------
// Backward scan over this group's batch-b slice of padded bf16 Yf->Z in place.
__device__ void back_scan_b(bf16* __restrict__ buf, int b, int gi){
  const size_t n8 = (size_t)2*PLANE/8;           // 76,832 uint4 per b-slice
  for (size_t i8 = (size_t)gi*256 + threadIdx.x; i8 < n8;
       i8 += (size_t)GRPBLK*256){
    size_t base = (size_t)b*2*PLANE + i8*8;
    float c[8];
#pragma unroll
    for (int e=0;e<8;e++) c[e]=0.f;
#pragma unroll
    for (int l = NL-1; l >= 0; l--){
      float al = a_of(l);
      uint4 v = *(const uint4*)(buf + (size_t)l*PL + base);
      bf16* hp = (bf16*)&v;
      uint4 o; bf16* ho = (bf16*)&o;
#pragma unroll
      for (int e=0;e<8;e++){
        float z = al*(al*c[e] + (float)hp[e]);
        ho[e] = (bf16)z; c[e] = z;
      }
      *(uint4*)(buf + (size_t)l*PL + base) = o;
    }
  }
}

// Final backward scan on this b's NCHW slice: zbase in place, out0 = Z[7].
__device__ void back_scan_final_b(float* __restrict__ zbase,
                                  float* __restrict__ out0, int b, int gi){
  const size_t nb = (size_t)64*IMG;              // 589,824 floats per b
  const size_t boff = (size_t)b*64*IMG;
  for (size_t idx = (size_t)gi*256 + threadIdx.x; idx < nb;
       idx += (size_t)GRPBLK*256){
    float c = 0.f;
#pragma unroll
    for (int i = NL-1; i >= 0; i--){
      float ai = a_of(i);
      float z = ai*(ai*c + zbase[(size_t)i*LSTRIDE + boff + idx]);
      zbase[(size_t)i*LSTRIDE + boff + idx] = z;
      if (i == NL-1) out0[boff + idx] = z;
      c = z;
    }
  }
}

// ---------------------------------------------------------------------------
// R11's conv_mfma verbatim as a device function (explicit rowg/b/h).
// MODE 0: in=Zq[l] -> dzq_out (padded bf16, LDS transpose) + fused stats
// MODE 1: in=dzq_in+stats; yv=-acc(+X/+X0); yf=a*(b*prev+yv) -> yfq_out
// MODE 2: same math fp32, direct NCHW stores to zb_out (final iteration)
template<int MODE>
__device__ void conv_body(char* smem, float (*sred)[32], float (*qred)[32],
    float2* stat_s, int rowg, int b, int h,
    const bf16* __restrict__ inq, const bf16* __restrict__ dzq_in,
    const bf16* __restrict__ apk,
    bf16* __restrict__ dzq_out, float* __restrict__ accstat,
    bf16* __restrict__ yfq_out, const bf16* __restrict__ yfq_prev,
    float* __restrict__ zb_out, const float* __restrict__ zb_prev,
    const float* __restrict__ Xadd, const float* __restrict__ X0add,
    float a_i, float b_i)
{
  char* Bbc = smem;                        // [4 rows][98 px][32 ic] bf16, swizzled
  char* Abc = smem + 25088;                // [3 taps][2 rep][32 oc][32 ic] bf16, swz

  const int y0 = rowg*2;
  const int tid = threadIdx.x;
  const int w = tid>>6, lane = tid&63;
  const int n16 = lane&15, q = lane>>4;
  const int wr = w>>1, wcol = (w&1)*48;
  const int yg = y0 + wr;

  if (MODE >= 1){   // finalize instance-norm stats for this b (padded slot)
    if (tid < 64){
      float s  = accstat[((size_t)b*64 + tid)*STAT_STRIDE];
      float s2 = accstat[((size_t)b*64 + tid)*STAT_STRIDE + 16];
      float m = s*(1.f/IMG);
      float vv = s2*(1.f/IMG) - m*m;
      if (vv < 0.f) vv = 0.f;
      stat_s[tid] = make_float2(m, rsqrtf(vv + EPS));
    }
    __syncthreads();
  }

  f32x4 acc[2][3];
#pragma unroll
  for (int a=0;a<2;a++)
#pragma unroll
    for (int c=0;c<3;c++){ f32x4 z = {0.f,0.f,0.f,0.f}; acc[a][c] = z; }

  for (int ch = 0; ch < 2; ch++){
    __syncthreads();
    if (MODE == 0){
      // stage 4 padded rows x 98 cols x 32 ic, swizzled 16B slots (raw bf16)
      const uint4* src = (const uint4*)(inq + (size_t)(b*2 + ch)*PLANE
                                            + (size_t)y0*PX*ICH);
      for (int i = tid; i < 1568; i += 256){
        int r = i / 392, rem = i - r*392;        // 392 uint4 per padded row
        int px = rem >> 2, slot = rem & 3;
        int s = (px & 3) ^ ((px >> 2) & 3);
        *(uint4*)(Bbc + (size_t)r*6272 + (size_t)px*64 + ((slot ^ s)<<4)) = src[i];
      }
    } else {
      // stage from padded bf16 dZq with fused normalize + leaky-relu
      const uint4* src = (const uint4*)(dzq_in + (size_t)(b*2 + ch)*PLANE
                                              + (size_t)y0*PX*ICH);
      for (int i = tid; i < 1568; i += 256){
        int r = i / 392, rem = i - r*392;
        int px = rem >> 2, slot = rem & 3;
        int s = (px & 3) ^ ((px >> 2) & 3);
        int ry = y0 + r;                  // padded row index (0 and 97 are pads)
        uint4 v = src[i];
        union { uint4 v; unsigned short u[8]; } o;
        if (ry >= 1 && ry <= 96 && px >= 1 && px <= 96){
          const unsigned short* hv = (const unsigned short*)&v;
#pragma unroll
          for (int k=0;k<8;k++){
            float2 mr = stat_s[ch*32 + slot*8 + k];
            float f = (float)*(const bf16*)&hv[k];
            float val = (f - mr.x)*mr.y;
            val = (val >= 0.f) ? val : 0.2f*val;
            bf16 hh = (bf16)val;
            o.u[k] = *(unsigned short*)&hh;
          }
        } else {
          o.v = make_uint4(0u,0u,0u,0u);
        }
        *(uint4*)(Bbc + (size_t)r*6272 + (size_t)px*64 + ((slot ^ s)<<4)) = o.v;
      }
    }
    for (int tg = 0; tg < 3; tg++){       // tap row groups (ky = tg)
      __syncthreads();
      { // stage 3 taps x 2 reps x 32 oc (this block's half) x 32 ic, swizzled
        const uint4* srcA = (const uint4*)(apk + (size_t)ch*36864);
        for (int i = tid; i < 768; i += 256){
          int chunk = i >> 7, j = i & 127;       // chunk = tap_r*2+rep, 128 u4/chunk
          int tap_r = chunk >> 1, rep = chunk & 1;
          int oc = j >> 2, slot = j & 3;
          int s = (oc & 3) ^ ((oc >> 2) & 3);
          *(uint4*)(Abc + (size_t)chunk*2048 + (size_t)oc*64 + ((slot ^ s)<<4))
              = srcA[((size_t)((tg*3 + tap_r)*2 + rep))*256 + h*128 + j];
        }
      }
      __syncthreads();
#pragma unroll
      for (int tj = 0; tj < 3; tj++){     // kx = tj
        const int ky = tg, kx = tj;
        bf16x8 Ah[2], Al[2];
#pragma unroll
        for (int mt=0;mt<2;mt++){
          int oc32 = mt*16 + n16;
          int sA = (oc32 & 3) ^ ((oc32 >> 2) & 3);
          Ah[mt] = *(const bf16x8*)(Abc + (size_t)(tj*2 + 0)*2048 + (size_t)oc32*64 + ((q ^ sA)<<4));
          Al[mt] = *(const bf16x8*)(Abc + (size_t)(tj*2 + 1)*2048 + (size_t)oc32*64 + ((q ^ sA)<<4));
        }
        bf16x8 Bf[3];
#pragma unroll
        for (int nt=0;nt<3;nt++){
          int px = wcol + nt*16 + n16 + kx;
          int sB = (px & 3) ^ ((px >> 2) & 3);
          Bf[nt] = *(const bf16x8*)(Bbc + (size_t)(wr + ky)*6272 + (size_t)px*64 + ((q ^ sB)<<4));
        }
#pragma unroll
        for (int nt=0;nt<3;nt++)
#pragma unroll
          for (int mt=0;mt<2;mt++)
            acc[mt][nt] = __builtin_amdgcn_mfma_f32_16x16x32_bf16(Ah[mt], Bf[nt], acc[mt][nt], 0,0,0);
#pragma unroll
        for (int nt=0;nt<3;nt++)
#pragma unroll
          for (int mt=0;mt<2;mt++)
            acc[mt][nt] = __builtin_amdgcn_mfma_f32_16x16x32_bf16(Al[mt], Bf[nt], acc[mt][nt], 0,0,0);
      }
    }
  }

  // ---------------- epilogue ----------------
  if (MODE >= 1){   // yv = -acc (+X at l=7) (+X0 at l=0)
#pragma unroll
    for (int mt=0;mt<2;mt++)
#pragma unroll
      for (int nt=0;nt<3;nt++){
        const int x = wcol + nt*16 + n16;
#pragma unroll
        for (int r=0;r<4;r++){
          const int oc = h*32 + mt*16 + q*4 + r;
          float v = -acc[mt][nt][r];
          if (Xadd)  v += Xadd[(((size_t)b*64 + oc)*96 + yg)*96 + x];
          if (X0add) v += X0add[((size_t)oc*96 + yg)*96 + x];
          acc[mt][nt][r] = v;
        }
      }
  }
  if (MODE == 2){   // final iter: fused forward scan, fp32 NCHW stores
#pragma unroll
    for (int mt=0;mt<2;mt++)
#pragma unroll
      for (int nt=0;nt<3;nt++){
        const int x = wcol + nt*16 + n16;
#pragma unroll
        for (int r=0;r<4;r++){
          const int oc = h*32 + mt*16 + q*4 + r;
          size_t idx = (((size_t)b*64 + oc)*96 + yg)*96 + x;
          float prev = (b_i != 0.f) ? zb_prev[idx] : 0.f;
          zb_out[idx] = a_i*(b_i*prev + acc[mt][nt][r]);
        }
      }
    return;
  }

  __syncthreads();                        // all waves done with Bbc/Abc
  float* T = (float*)smem + w*1584;       // per-wave 48 x 33 fp32 transpose tile
#pragma unroll
  for (int mt2=0; mt2<2; mt2++)
#pragma unroll
    for (int nt=0;nt<3;nt++)
#pragma unroll
      for (int r=0;r<4;r++)
        T[(nt*16 + n16)*33 + mt2*16 + q*4 + r] = acc[mt2][nt][r];

  float s4[4] = {0.f,0.f,0.f,0.f};        // MODE 0: per-lane stats (acc now dead)
  float q4[4] = {0.f,0.f,0.f,0.f};
  for (int f = lane; f < 384; f += 64){
    int px = f>>3, c4 = (f&7)*4;
    float vv[4];
#pragma unroll
    for (int k=0;k<4;k++) vv[k] = T[px*33 + c4 + k];
    int x = wcol + px;
    if (MODE == 0){
      // store raw dZ as bf16 into the padded layout (stats stay fp32-exact)
      size_t off = ((size_t)(b*2 + h)*PY + (yg+1))*(size_t)PX*ICH
                 + (size_t)(x+1)*ICH + c4;
      union { uint2 v; unsigned short u[4]; } oo;
#pragma unroll
      for (int k=0;k<4;k++){
        bf16 hh = (bf16)vv[k];
        oo.u[k] = *(unsigned short*)&hh;
        s4[k] += vv[k]; q4[k] += vv[k]*vv[k];
      }
      *(uint2*)(dzq_out + off) = oo.v;
    } else {
      size_t off = ((size_t)(b*2 + h)*PY + (yg+1))*(size_t)PX*ICH
                 + (size_t)(x+1)*ICH + c4;
      uint2 pv = *(const uint2*)(yfq_prev + off);
      bf16* ph = (bf16*)&pv;
      union { uint2 v; unsigned short u[4]; } o;
#pragma unroll
      for (int k=0;k<4;k++){
        float yf = a_i*(b_i*(float)ph[k] + vv[k]);
        bf16 hh = (bf16)yf;
        o.u[k] = *(unsigned short*)&hh;
      }
      *(uint2*)(yfq_out + off) = o.v;
    }
  }

  if (MODE == 0){
    // lanes sharing (lane&7) hold partials for the same 4 channels: xor 8/16/32
#pragma unroll
    for (int st = 8; st < 64; st <<= 1)
#pragma unroll
      for (int k=0;k<4;k++){
        s4[k] += __shfl_xor(s4[k], st, 64);
        q4[k] += __shfl_xor(q4[k], st, 64);
      }
    if (lane < 8){
#pragma unroll
      for (int k=0;k<4;k++){
        sred[w][lane*4 + k] = s4[k];
        qred[w][lane*4 + k] = q4[k];
      }
    }
    __syncthreads();
    if (tid < 32){
      float ss = sred[0][tid] + sred[1][tid] + sred[2][tid] + sred[3][tid];
      float qq = qred[0][tid] + qred[1][tid] + qred[2][tid] + qred[3][tid];
      size_t base = ((size_t)b*64 + h*32 + tid)*STAT_STRIDE;
      atomicAdd(&accstat[base], ss);
      atomicAdd(&accstat[base + 16], qq);
    }
  }
}

// ---------------------------------------------------------------------------
// R14: persistent kernel, 8 independent batch-groups of 96 blocks; barriers
// group-local with padded slots + parallel-lane master polling (R13's serial
// sweep was ~48us/pass). Groups drift freely; straggler tails overlap.
__global__ __launch_bounds__(256, 3) void fused_all(
    bf16* __restrict__ Zq, bf16* __restrict__ dZq2,
    const bf16* __restrict__ apf, const bf16* __restrict__ apb,
    float* __restrict__ statacc,
    const float* __restrict__ X, const float* __restrict__ X0,
    float* __restrict__ zbase, float* __restrict__ out0,
    unsigned* __restrict__ sync)
{
  __shared__ __align__(16) char smem[25088 + 12288];
  __shared__ float sred[4][32];
  __shared__ float qred[4][32];
  __shared__ float2 stat_s[64];

  const int gb = blockIdx.x / GRPBLK;     // batch group (= b)
  const int gi = blockIdx.x % GRPBLK;     // index within group
  const int rowg = gi % 48, h = gi / 48;
  unsigned* gslots = sync + (size_t)gb*SYNC_GRP_U;   // 96 x 128B slots
  unsigned* ggen   = gslots + GRPBLK*32;             // own cache line
  unsigned ph = 0;

  // initial backward scan Yf(it=0) -> Z for this b (init_yf_t ran before us)
  back_scan_b(Zq, gb, gi);
  group_sync(gslots, ggen, gi, ++ph);

  for (int it = 1; it <= 3; ++it){
    for (int l = 0; l < NL; ++l){
      float* accs = statacc + (size_t)((it-1)*NL + l)*STAT_SLOT;
      bf16* dq = dZq2 + (size_t)(l & 1)*PL;
      conv_body<0>(smem, sred, qred, stat_s, rowg, gb, h,
                   Zq + (size_t)l*PL, nullptr, apf + (size_t)l*APK_L,
                   dq, accs, nullptr, nullptr, nullptr, nullptr,
                   nullptr, nullptr, 0.f, 0.f);
      group_sync(gslots, ggen, gi, ++ph);      // stats + dZq halo ready
      float ai = a_of(l), bi = b_of(l);
      const float* Xa  = (l==NL-1) ? X  : nullptr;
      const float* X0a = (l==0)    ? X0 : nullptr;
      if (it < 3)
        conv_body<1>(smem, sred, qred, stat_s, rowg, gb, h,
                     nullptr, dq, apb + (size_t)l*APK_L,
                     nullptr, accs,
                     Zq + (size_t)l*PL, Zq + (size_t)(l>0?l-1:0)*PL,
                     nullptr, nullptr, Xa, X0a, ai, bi);
      else
        conv_body<2>(smem, sred, qred, stat_s, rowg, gb, h,
                     nullptr, dq, apb + (size_t)l*APK_L,
                     nullptr, accs, nullptr, nullptr,
                     zbase + (size_t)l*LSTRIDE, zbase + (size_t)(l>0?l-1:0)*LSTRIDE,
                     Xa, X0a, ai, bi);
      // no barrier B(l)->A(l+1): disjoint tensors (dZq ping-pong; Zq layers)
    }
    group_sync(gslots, ggen, gi, ++ph);        // B writes done
    if (it < 3){
      back_scan_b(Zq, gb, gi);
      group_sync(gslots, ggen, gi, ++ph);      // scan writes done
    } else {
      back_scan_final_b(zbase, out0, gb, gi);
    }
  }
}

// ---------------------------------------------------------------------------
extern "C" void kernel_launch(void* const* d_in, const int* in_sizes, int n_in,
                              void* d_out, int out_size, void* d_ws, size_t ws_size,
                              hipStream_t stream) {
  const float* X  = (const float*)d_in[0];
  const float* K  = (const float*)d_in[1];
  const float* X0 = (const float*)d_in[2];

  float* out0  = (float*)d_out;
  float* zbase = out0 + LSTRIDE;

  char* ws = (char*)d_ws;
  float*    statacc = (float*)ws;                       // 24 x 64KB padded slots
  unsigned* syncv   = (unsigned*)(ws + 24*STAT_SLOT*4); // 8 x SYNC_GRP_U uints
  bf16*     apf     = (bf16*)(ws + 24*STAT_SLOT*4 + 8*SYNC_GRP_U*4);
  bf16*     apb     = apf + (size_t)NL*APK_L;
  bf16*     Zq      = apb + (size_t)NL*APK_L;           // 8*PL (doubles as Yfq)
  bf16*     dZq2    = Zq + (size_t)NL*PL;               // 2*PL ping-pong

  // zero stats slots + barrier state (inside graph -> clean each replay)
  hipMemsetAsync(statacc, 0, 24*STAT_SLOT*4 + 8*SYNC_GRP_U*4, stream);
  hipMemsetAsync(Zq, 0, (size_t)NL*PL*2, stream);       // zero pads

  pack_weights<<<(NL*9*4096 + 255)/256, 256, 0, stream>>>(K, apf, apb);
  init_yf_t<<<dim3(HC, BB), 256, 0, stream>>>(X, X0, Zq);

  fused_all<<<NBLK, 256, 0, stream>>>(
      Zq, dZq2, apf, apb, statacc, X, X0, zbase, out0, syncv);
}